// Round 20
// baseline (206.772 us; speedup 1.0000x reference)
//
#include <hip/hip_runtime.h>
#include <hip/hip_bf16.h>
#include <math.h>

#define N_NODES 100000
#define N_EDGES 3200000
#define IN_F    512
#define HID     16
#define NCLS    40
#define NB      512    // node buckets
#define NPB     196    // nodes per bucket (512*196 = 100352 >= 100000)
#define CAPW    8192   // words per bucket region (mean 6250, sigma 79; 24-sigma)
#define NBLK    1024   // binning blocks (4/CU -> 16 waves/CU)
#define EPB     3125   // edges per binning block (1024*3125 = 3.2M exactly)
#define EPT     13     // ceil(EPB/256) edges per thread (register dst cache)

typedef unsigned short ushort_t;
struct ushort4_t { ushort_t x, y, z, w; };

__device__ __forceinline__ float bf16_to_f32(ushort_t u) {
    unsigned int b = ((unsigned int)u) << 16;
    return __uint_as_float(b);
}
__device__ __forceinline__ ushort_t f32_to_bf16(float f) {
    __hip_bfloat16 h = __float2bfloat16(f);  // RTNE
    return *(ushort_t*)&h;
}

__device__ __forceinline__ int load_edge(const void* ei, int is64, int idx) {
    if (is64) return (int)((const long long*)ei)[idx];
    return ((const int*)ei)[idx];
}

// ---------------- fused: dtype sniff (block 0) + cursor init -----------------
__global__ __launch_bounds__(256) void kPre(const int* __restrict__ ei,
                                            int* __restrict__ flag,
                                            int* __restrict__ gcur) {
    int i = blockIdx.x * 256 + threadIdx.x;
    if (i < NB) gcur[i] = i * CAPW;
    if (blockIdx.x == 0) {
        __shared__ int s_nz;
        if (threadIdx.x == 0) s_nz = 0;
        __syncthreads();
        int nz = 0;
        for (int k = threadIdx.x; k < 1024; k += 256)
            if (ei[2 * k + 1] != 0) nz = 1;
        if (nz) atomicOr(&s_nz, 1);
        __syncthreads();
        if (threadIdx.x == 0) flag[0] = s_nz ? 0 : 1;  // 1 => int64 layout
    }
}

// ---------------- bin edges into fixed-capacity bucket regions ---------------
// packed word = (src << 8) | dst_local   (src < 2^17, dst_local < 196 < 256)
__global__ __launch_bounds__(256) void kB(const void* __restrict__ ei,
                                          const int* __restrict__ flag,
                                          int* __restrict__ gcur,
                                          int* __restrict__ binned) {
    __shared__ int hist[NB];
    __shared__ int base[NB];
    int tid = threadIdx.x;
    for (int i = tid; i < NB; i += 256) hist[i] = 0;
    __syncthreads();
    int is64 = flag[0];
    int off0 = blockIdx.x * EPB;
    int dreg[EPT];
#pragma unroll
    for (int u = 0; u < EPT; ++u) {
        int i = u * 256 + tid;
        if (i < EPB) {
            int d = load_edge(ei, is64, N_EDGES + off0 + i);
            dreg[u] = d;
            atomicAdd(&hist[d / NPB], 1);
        } else {
            dreg[u] = -1;
        }
    }
    __syncthreads();
    for (int i = tid; i < NB; i += 256) {
        int c = hist[i];
        base[i] = c ? atomicAdd(&gcur[i], c) : 0;
        hist[i] = 0;  // becomes local cursor
    }
    __syncthreads();
#pragma unroll
    for (int u = 0; u < EPT; ++u) {
        int i = u * 256 + tid;
        if (i < EPB) {
            int s = load_edge(ei, is64, off0 + i);
            int d = dreg[u];
            int b = d / NPB;
            int o = atomicAdd(&hist[b], 1);
            binned[base[b] + o] = (s << 8) | (d - b * NPB);
        }
    }
}

// ---------------- second-level sort: bucket -> exact per-node CSR ------------
__global__ __launch_bounds__(256) void kSort(const int* __restrict__ gcur,
                                             int* __restrict__ binned,
                                             int* __restrict__ nstart,
                                             int* __restrict__ bend,
                                             float* __restrict__ dinv) {
    __shared__ int elist[CAPW];     // 32 KB
    __shared__ int ih[NPB];
    __shared__ int lscan[NPB + 1];
    int b = blockIdx.x, tid = threadIdx.x;
    int beg = b * CAPW;
    int cnt = gcur[b] - beg;
    if (cnt > CAPW) cnt = CAPW;   // 24-sigma clamp; never fires on uniform data
    if (cnt < 0) cnt = 0;
    if (tid < NPB) ih[tid] = 0;
    __syncthreads();
    for (int k = tid; k < cnt; k += 256) {
        int p = binned[beg + k];
        elist[k] = p;
        atomicAdd(&ih[p & 255], 1);
    }
    __syncthreads();
    if (tid == 0) {
        int run = 0;
        for (int i = 0; i < NPB; ++i) { lscan[i] = run; run += ih[i]; }
        lscan[NPB] = run;
        bend[b] = beg + run;
    }
    __syncthreads();
    if (tid < NPB) {
        int n = b * NPB + tid;
        if (n < N_NODES) dinv[n] = rsqrtf((float)(ih[tid] + 1));  // +1 self loop
        nstart[n] = beg + lscan[tid];
        ih[tid] = lscan[tid];           // becomes cursor (own-index RMW)
    }
    __syncthreads();
    for (int k = tid; k < cnt; k += 256) {
        int p = elist[k];
        int pos = atomicAdd(&ih[p & 255], 1);
        binned[beg + pos] = p >> 8;  // store src only, dst implied by segment
    }
}

// ---------------- layer 1 GEMM: hsb = bf16( (x @ W1) * dinv[n] ) -------------
// 4-deep x-load batching (round-19 proven form, unchanged).
__global__ __launch_bounds__(128) void k_gemm1(const float* __restrict__ x,
                                               const float* __restrict__ W1,
                                               const float* __restrict__ dinv,
                                               ushort_t* __restrict__ hsb) {
    __shared__ float Ws[IN_F * HID];  // 32 KB
    for (int i = threadIdx.x; i < IN_F * HID; i += 128) Ws[i] = W1[i];
    __syncthreads();
    int n = blockIdx.x * 128 + threadIdx.x;
    if (n >= N_NODES) return;
    float acc[HID];
#pragma unroll
    for (int j = 0; j < HID; ++j) acc[j] = 0.0f;
    const float4* xr = (const float4*)(x + (size_t)n * IN_F);
    for (int k16 = 0; k16 < IN_F / 16; ++k16) {
        float4 xv[4];
#pragma unroll
        for (int q = 0; q < 4; ++q) xv[q] = xr[k16 * 4 + q];  // 4 loads in flight
#pragma unroll
        for (int q = 0; q < 4; ++q) {
            int kb = (k16 * 4 + q) * 4;
#pragma unroll
            for (int i = 0; i < 4; ++i) {
                float xs = (&xv[q].x)[i];
                const float4* wr = (const float4*)(Ws + (kb + i) * HID);
#pragma unroll
                for (int j4 = 0; j4 < 4; ++j4) {
                    float4 w = wr[j4];  // same addr across lanes -> broadcast
                    acc[j4 * 4 + 0] += xs * w.x;
                    acc[j4 * 4 + 1] += xs * w.y;
                    acc[j4 * 4 + 2] += xs * w.z;
                    acc[j4 * 4 + 3] += xs * w.w;
                }
            }
        }
    }
    float di = dinv[n];
    ushort_t* hn = hsb + (size_t)n * HID;
#pragma unroll
    for (int j = 0; j < HID; ++j) hn[j] = f32_to_bf16(acc[j] * di);
}

// ---------------- gather core: 4 lanes/edge, ushort4 loads -------------------
// Group of 16 lanes per node; lane = 4*esub + f4. Per load instruction a wave
// covers 16 edges (vs 4 with the 2B scheme). 16-edge chunks, index prefetch.
// Returns this lane's f4-slice sums reduced over esub (valid on all lanes).
__device__ __forceinline__ void gather_sum4(const int* __restrict__ sorted,
                                            int beg, int end,
                                            const ushort_t* __restrict__ feat,
                                            int esub, int f4,
                                            float* __restrict__ r) {
    float ax = 0.0f, ay = 0.0f, az = 0.0f, aw = 0.0f;
    int k = beg;
    if (k + 16 <= end) {
        int s[4];
#pragma unroll
        for (int u = 0; u < 4; ++u) s[u] = sorted[k + 4 * u + esub];
        for (; k + 32 <= end; k += 16) {
            int s2[4];
#pragma unroll
            for (int u = 0; u < 4; ++u) s2[u] = sorted[k + 16 + 4 * u + esub];
#pragma unroll
            for (int u = 0; u < 4; ++u) {
                ushort4_t v = *(const ushort4_t*)&feat[(size_t)s[u] * HID + 4 * f4];
                ax += bf16_to_f32(v.x); ay += bf16_to_f32(v.y);
                az += bf16_to_f32(v.z); aw += bf16_to_f32(v.w);
            }
#pragma unroll
            for (int u = 0; u < 4; ++u) s[u] = s2[u];
        }
#pragma unroll
        for (int u = 0; u < 4; ++u) {
            ushort4_t v = *(const ushort4_t*)&feat[(size_t)s[u] * HID + 4 * f4];
            ax += bf16_to_f32(v.x); ay += bf16_to_f32(v.y);
            az += bf16_to_f32(v.z); aw += bf16_to_f32(v.w);
        }
        k += 16;
    }
    for (; k + 4 <= end; k += 4) {
        int s = sorted[k + esub];
        ushort4_t v = *(const ushort4_t*)&feat[(size_t)s * HID + 4 * f4];
        ax += bf16_to_f32(v.x); ay += bf16_to_f32(v.y);
        az += bf16_to_f32(v.z); aw += bf16_to_f32(v.w);
    }
    if (k + esub < end) {
        int s = sorted[k + esub];
        ushort4_t v = *(const ushort4_t*)&feat[(size_t)s * HID + 4 * f4];
        ax += bf16_to_f32(v.x); ay += bf16_to_f32(v.y);
        az += bf16_to_f32(v.z); aw += bf16_to_f32(v.w);
    }
    // reduce over esub (lane bits 2,3 within the 16-lane group)
#pragma unroll
    for (int m = 4; m <= 8; m <<= 1) {
        ax += __shfl_xor(ax, m, 16);
        ay += __shfl_xor(ay, m, 16);
        az += __shfl_xor(az, m, 16);
        aw += __shfl_xor(aw, m, 16);
    }
    r[0] = ax; r[1] = ay; r[2] = az; r[3] = aw;
}

// ---------------- layer-1 aggregation (gather, register acc, NO atomics) -----
__global__ __launch_bounds__(256) void kAgg1(const int* __restrict__ nstart,
                                             const int* __restrict__ bend,
                                             const int* __restrict__ sorted,
                                             const ushort_t* __restrict__ hsb,
                                             const float* __restrict__ dinv,
                                             const float* __restrict__ b1,
                                             ushort_t* __restrict__ h1sb) {
    int tid = threadIdx.x;
    int g = tid >> 4, lane = tid & 15;
    int esub = lane >> 2, f4 = lane & 3;
    int n = blockIdx.x * 16 + g;
    int b = n / NPB, il = n - b * NPB;
    int beg = nstart[n];
    int end = (il == NPB - 1) ? bend[b] : nstart[n + 1];
    float r[4];
    gather_sum4(sorted, beg, end, hsb, esub, f4, r);
    if (esub == 0) {
        float di = dinv[n];
        ushort4_t sv = *(const ushort4_t*)&hsb[(size_t)n * HID + 4 * f4];
        float s0 = bf16_to_f32(sv.x), s1 = bf16_to_f32(sv.y);
        float s2 = bf16_to_f32(sv.z), s3 = bf16_to_f32(sv.w);
        const float* bp = b1 + 4 * f4;
        ushort4_t o;
        o.x = f32_to_bf16(fmaxf(di * (r[0] + s0) + bp[0], 0.0f) * di);
        o.y = f32_to_bf16(fmaxf(di * (r[1] + s1) + bp[1], 0.0f) * di);
        o.z = f32_to_bf16(fmaxf(di * (r[2] + s2) + bp[2], 0.0f) * di);
        o.w = f32_to_bf16(fmaxf(di * (r[3] + s3) + bp[3], 0.0f) * di);
        *(ushort4_t*)&h1sb[(size_t)n * HID + 4 * f4] = o;
    }
}

// ---------------- fused layer-2 aggregation + W2 + log_softmax ---------------
__global__ __launch_bounds__(256) void kAggOut(const int* __restrict__ nstart,
                                               const int* __restrict__ bend,
                                               const int* __restrict__ sorted,
                                               const ushort_t* __restrict__ h1sb,
                                               const float* __restrict__ dinv,
                                               const float* __restrict__ W2,
                                               const float* __restrict__ b2,
                                               float* __restrict__ out) {
    __shared__ float a2[16][HID + 1];
    __shared__ float Ws[HID * NCLS];
    __shared__ float bs[NCLS];
    int tid = threadIdx.x;
    for (int i = tid; i < HID * NCLS; i += 256) Ws[i] = W2[i];
    for (int i = tid; i < NCLS; i += 256) bs[i] = b2[i];

    int g = tid >> 4, lane = tid & 15;
    int esub = lane >> 2, f4 = lane & 3;
    int n = blockIdx.x * 16 + g;
    int b = n / NPB, il = n - b * NPB;
    int beg = nstart[n];
    int end = (il == NPB - 1) ? bend[b] : nstart[n + 1];
    float r[4];
    gather_sum4(sorted, beg, end, h1sb, esub, f4, r);
    if (esub == 0) {
        float di = dinv[n];
        ushort4_t sv = *(const ushort4_t*)&h1sb[(size_t)n * HID + 4 * f4];
        a2[g][4 * f4 + 0] = di * (r[0] + bf16_to_f32(sv.x));
        a2[g][4 * f4 + 1] = di * (r[1] + bf16_to_f32(sv.y));
        a2[g][4 * f4 + 2] = di * (r[2] + bf16_to_f32(sv.z));
        a2[g][4 * f4 + 3] = di * (r[3] + bf16_to_f32(sv.w));
    }
    __syncthreads();

    float l0 = bs[lane], l1 = bs[lane + 16];
    float l2 = (lane < 8) ? bs[lane + 32] : -1e30f;
#pragma unroll
    for (int j = 0; j < HID; ++j) {
        float av = a2[g][j];
        const float* wr = Ws + j * NCLS;
        l0 += av * wr[lane];
        l1 += av * wr[lane + 16];
        if (lane < 8) l2 += av * wr[lane + 32];
    }
    float m = fmaxf(l0, fmaxf(l1, l2));
#pragma unroll
    for (int off = 8; off >= 1; off >>= 1)
        m = fmaxf(m, __shfl_xor(m, off, 16));
    float e = expf(l0 - m) + expf(l1 - m) + ((lane < 8) ? expf(l2 - m) : 0.0f);
#pragma unroll
    for (int off = 8; off >= 1; off >>= 1)
        e += __shfl_xor(e, off, 16);
    float lse = m + logf(e);
    float* on = out + (size_t)n * NCLS;
    on[lane] = l0 - lse;
    on[lane + 16] = l1 - lse;
    if (lane < 8) on[lane + 32] = l2 - lse;
}

// ---------------- launch -----------------------------------------------------
extern "C" void kernel_launch(void* const* d_in, const int* in_sizes, int n_in,
                              void* d_out, int out_size, void* d_ws, size_t ws_size,
                              hipStream_t stream) {
    const float* x  = (const float*)d_in[0];
    const void*  ei = d_in[1];
    const float* W1 = (const float*)d_in[2];
    const float* b1 = (const float*)d_in[3];
    const float* W2 = (const float*)d_in[4];
    const float* b2 = (const float*)d_in[5];
    float* out = (float*)d_out;

    // workspace layout (32-bit words)
    int*      iws    = (int*)d_ws;
    float*    fws    = (float*)d_ws;
    int*      gcur   = iws;                          // [512] region cursors
    int*      bend   = iws + 2048;                   // [512]
    int*      flag   = iws + 4096;                   // [1]
    float*    dinv   = fws + 8192;                   // [100000]
    int*      nstart = iws + 108192;                 // [100352]
    ushort_t* hsb    = (ushort_t*)(iws + 212992);    // [1.6M bf16]
    ushort_t* h1sb   = (ushort_t*)(iws + 1012992);   // [1.6M bf16]
    int*      binned = iws + 1812992;                // [NB*CAPW = 4.19M]

    const int B = 256;

    kPre<<<(NB + B - 1) / B, B, 0, stream>>>((const int*)ei, flag, gcur);
    kB<<<NBLK, B, 0, stream>>>(ei, flag, gcur, binned);
    kSort<<<NB, B, 0, stream>>>(gcur, binned, nstart, bend, dinv);
    k_gemm1<<<(N_NODES + 127) / 128, 128, 0, stream>>>(x, W1, dinv, hsb);
    kAgg1<<<N_NODES / 16, B, 0, stream>>>(nstart, bend, binned, hsb, dinv, b1, h1sb);
    kAggOut<<<N_NODES / 16, B, 0, stream>>>(nstart, bend, binned, h1sb, dinv, W2, b2, out);
}